// Round 16
// baseline (455.429 us; speedup 1.0000x reference)
//
#include <hip/hip_runtime.h>
#include <hip/hip_bf16.h>
#include <math.h>

#define B 4
#define C 256
#define H 256
#define Wd 256

// ---------------------------------------------------------------------------
// K1: plane-per-block streaming pass (measured: 52.4 us cold, 5.1 TB/s, ~81%
// of achievable BW -> near-roofline; unchanged).
// ---------------------------------------------------------------------------
__global__ __launch_bounds__(256) void xreadproj_kernel(
    const float* __restrict__ x,
    float* __restrict__ pool16, float* __restrict__ xp16o,
    float* __restrict__ xp8o, float* __restrict__ xp4o,
    float* __restrict__ sx) {

    __shared__ float P0[16][72];    // p0; guards [64..71]=0
    __shared__ float SS16[16][68];  // [2+l]=S16; guards [0..1],[66..67]=0
    __shared__ float SS8[16][72];   // [4+l]=S8;  guards [0..3],[68..71]=0
    __shared__ float SS4[16][80];   // [8+l]=S4;  guards [0..7],[72..79]=0
    __shared__ float Rs[16 * 29];   // per-slab rowproj, padded stride 29
    __shared__ float rs[4][2];

    int bc = blockIdx.x;
    int t = threadIdx.x;
    int wg = t >> 6, l = t & 63;

    const float4* xp = (const float4*)(x + (size_t)bc * (H * Wd));

    // guard zeros (36 per row; persist across slabs)
    for (int e = t; e < 576; e += 256) {
        int r = e / 36, g = e - r * 36;
        if (g < 8)       P0[r][64 + g] = 0.f;
        else if (g < 10) SS16[r][g - 8] = 0.f;
        else if (g < 12) SS16[r][56 + g] = 0.f;        // 66,67
        else if (g < 16) SS8[r][g - 12] = 0.f;
        else if (g < 20) SS8[r][52 + g] = 0.f;         // 68..71
        else if (g < 28) SS4[r][g - 20] = 0.f;
        else             SS4[r][44 + g] = 0.f;         // 72..79
    }

    // per-lane w-side constants (validated)
    float a16, b16, a8, b8, a4, b4;
    {
        float w0 = 4.f * (float)l + 0.5f;
        float s16v = w0 * 0.0625f - 0.5f;
        if (l <= 1 || l >= 62) { a16 = 0.f; b16 = 0.f; }
        else { a16 = s16v - floorf(s16v); b16 = 0.0625f; }
        float s8v = w0 * 0.03125f - 0.5f;
        if (l <= 3 || l >= 60) { a8 = 0.f; b8 = 0.f; }
        else { a8 = s8v - floorf(s8v); b8 = 0.03125f; }
        float s4v = w0 * 0.015625f - 0.5f;
        if (l <= 7 || l >= 56) { a4 = 0.f; b4 = 0.f; }
        else { a4 = s4v - floorf(s4v); b4 = 0.015625f; }
    }

    // fold-owner indices
    const int i16 = t >> 4, j16 = t & 15;
    const int i8 = t >> 3, j8 = t & 7;              // valid for t<64
    const int i4 = (t - 64) >> 2, j4 = (t - 64) & 3; // valid for 64<=t<80

    float accA = 0.f;   // xp16 entry
    float accB = 0.f;   // xp8 (t<64) or xp4 (64<=t<80)
    float sx1 = 0.f, sx2 = 0.f;

    float4 v[4], vn[4];
#pragma unroll
    for (int it = 0; it < 4; ++it)
        v[it] = xp[(wg * 4 + it) * 64 + l];

#pragma unroll 1
    for (int k = 0; k < 16; ++k) {
        // ---- fold slab k-1 from Rs (validated windows; ascending r) ----
        if (k > 0) {
            int kk = k - 1;
            if (kk >= i16 - 1 && kk <= i16 + 1) {
#pragma unroll
                for (int rl = 0; rl < 16; ++rl) {
                    float src = ((float)(kk * 16 + rl) + 0.5f) * 0.0625f - 0.5f;
                    src = fminf(fmaxf(src, 0.f), 15.f);
                    int lo = (int)src; float fr = src - (float)lo;
                    float w = (i16 == lo) ? (1.f - fr) : ((i16 == lo + 1) ? fr : 0.f);
                    accA += w * Rs[rl * 29 + j16];
                }
            }
            if (t < 64) {
                if (kk >= 2 * i8 - 1 && kk <= 2 * i8 + 2) {
#pragma unroll
                    for (int rl = 0; rl < 16; ++rl) {
                        float src = ((float)(kk * 16 + rl) + 0.5f) * 0.03125f - 0.5f;
                        src = fminf(fmaxf(src, 0.f), 7.f);
                        int lo = (int)src; float fr = src - (float)lo;
                        float w = (i8 == lo) ? (1.f - fr) : ((i8 == lo + 1) ? fr : 0.f);
                        accB += w * Rs[rl * 29 + 16 + j8];
                    }
                }
            } else if (t < 80) {
                if (kk >= 4 * i4 - 2 && kk <= 4 * i4 + 5) {
#pragma unroll
                    for (int rl = 0; rl < 16; ++rl) {
                        float src = ((float)(kk * 16 + rl) + 0.5f) * 0.015625f - 0.5f;
                        src = fminf(fmaxf(src, 0.f), 3.f);
                        int lo = (int)src; float fr = src - (float)lo;
                        float w = (i4 == lo) ? (1.f - fr) : ((i4 == lo + 1) ? fr : 0.f);
                        accB += w * Rs[rl * 29 + 24 + j4];
                    }
                }
            }
        }

        // ---- stage slab k (P0/S only) + sx ----
#pragma unroll
        for (int it = 0; it < 4; ++it) {
            int r = wg * 4 + it;
            float4 vv = v[it];
            float p0 = (vv.x + vv.y) + (vv.z + vv.w);
            float pw = fmaf(3.f, vv.w, fmaf(2.f, vv.z, vv.y));
            sx1 += p0;
            sx2 += vv.x * vv.x + vv.y * vv.y + vv.z * vv.z + vv.w * vv.w;
            P0[r][l]       = p0;
            SS16[r][2 + l] = fmaf(b16, pw, a16 * p0);
            SS8[r][4 + l]  = fmaf(b8,  pw, a8  * p0);
            SS4[r][8 + l]  = fmaf(b4,  pw, a4  * p0);
        }
        __syncthreads();     // barrier A

        // ---- prefetch slab k+1 (after barrier A) ----
        if (k < 15) {
#pragma unroll
            for (int it = 0; it < 4; ++it)
                vn[it] = xp[((k + 1) * 16 + wg * 4 + it) * 64 + l];
        }

        // ---- merge slab k: staging -> Rs + pool16 (validated sums) ----
        for (int tk = t; tk < 464; tk += 256) {
            if (tk < 256) {                       // s16
                int r = tk >> 4, j = tk & 15;
                float sum = 0.f;
#pragma unroll
                for (int q = 0; q < 4; ++q)
                    sum += P0[r][4 * j + 2 + q] - SS16[r][4 * j + 4 + q];
#pragma unroll
                for (int q = 0; q < 4; ++q) sum += SS16[r][4 * j + q];
                if (j == 0) sum += (P0[r][0] - SS16[r][2]) + (P0[r][1] - SS16[r][3]);
                Rs[r * 29 + j] = sum;
            } else if (tk < 384) {                // s8
                int q2 = tk - 256; int r = q2 >> 3, j = q2 & 7;
                float sum = 0.f;
#pragma unroll
                for (int q = 0; q < 8; ++q)
                    sum += P0[r][8 * j + 4 + q] - SS8[r][8 * j + 8 + q];
#pragma unroll
                for (int q = 0; q < 8; ++q) sum += SS8[r][8 * j + q];
                if (j == 0) {
#pragma unroll
                    for (int q = 0; q < 4; ++q) sum += P0[r][q] - SS8[r][4 + q];
                }
                Rs[r * 29 + 16 + j] = sum;
            } else if (tk < 448) {                // s4
                int q2 = tk - 384; int r = q2 >> 2, j = q2 & 3;
                float sum = 0.f;
#pragma unroll
                for (int q = 0; q < 16; ++q)
                    sum += P0[r][16 * j + 8 + q] - SS4[r][16 * j + 16 + q];
#pragma unroll
                for (int q = 0; q < 16; ++q) sum += SS4[r][16 * j + q];
                if (j == 0) {
#pragma unroll
                    for (int q = 0; q < 8; ++q) sum += P0[r][q] - SS4[r][8 + q];
                }
                Rs[r * 29 + 24 + j] = sum;
            } else {                              // pool row
                int j = tk - 448;
                float sum = 0.f;
#pragma unroll
                for (int r2 = 0; r2 < 16; ++r2) {
#pragma unroll
                    for (int q = 0; q < 4; ++q) sum += P0[r2][4 * j + q];
                }
                pool16[(size_t)bc * 256 + k * 16 + j] = sum * (1.f / 256.f);
            }
        }
        __syncthreads();     // barrier B
#pragma unroll
        for (int it = 0; it < 4; ++it) v[it] = vn[it];
    }

    // ---- fold last slab (15) ----
    {
        int kk = 15;
        if (kk >= i16 - 1 && kk <= i16 + 1) {
#pragma unroll
            for (int rl = 0; rl < 16; ++rl) {
                float src = ((float)(kk * 16 + rl) + 0.5f) * 0.0625f - 0.5f;
                src = fminf(fmaxf(src, 0.f), 15.f);
                int lo = (int)src; float fr = src - (float)lo;
                float w = (i16 == lo) ? (1.f - fr) : ((i16 == lo + 1) ? fr : 0.f);
                accA += w * Rs[rl * 29 + j16];
            }
        }
        if (t < 64) {
            if (kk >= 2 * i8 - 1 && kk <= 2 * i8 + 2) {
#pragma unroll
                for (int rl = 0; rl < 16; ++rl) {
                    float src = ((float)(kk * 16 + rl) + 0.5f) * 0.03125f - 0.5f;
                    src = fminf(fmaxf(src, 0.f), 7.f);
                    int lo = (int)src; float fr = src - (float)lo;
                    float w = (i8 == lo) ? (1.f - fr) : ((i8 == lo + 1) ? fr : 0.f);
                    accB += w * Rs[rl * 29 + 16 + j8];
                }
            }
        } else if (t < 80) {
            if (kk >= 4 * i4 - 2 && kk <= 4 * i4 + 5) {
#pragma unroll
                for (int rl = 0; rl < 16; ++rl) {
                    float src = ((float)(kk * 16 + rl) + 0.5f) * 0.015625f - 0.5f;
                    src = fminf(fmaxf(src, 0.f), 3.f);
                    int lo = (int)src; float fr = src - (float)lo;
                    float w = (i4 == lo) ? (1.f - fr) : ((i4 == lo + 1) ? fr : 0.f);
                    accB += w * Rs[rl * 29 + 24 + j4];
                }
            }
        }
    }

    xp16o[(size_t)bc * 256 + t] = accA;
    if (t < 64) xp8o[(size_t)bc * 64 + t] = accB;
    else if (t < 80) xp4o[(size_t)bc * 16 + (t - 64)] = accB;

    // sx: wave reduce (validated pattern)
#pragma unroll
    for (int off = 1; off < 64; off <<= 1) {
        sx1 += __shfl_xor(sx1, off);
        sx2 += __shfl_xor(sx2, off);
    }
    if (l == 0) { rs[wg][0] = sx1; rs[wg][1] = sx2; }
    __syncthreads();
    if (t == 0) {
        sx[bc * 2]     = rs[0][0] + rs[1][0] + rs[2][0] + rs[3][0];
        sx[bc * 2 + 1] = rs[0][1] + rs[1][1] + rs[2][1] + rs[3][1];
    }
}

// ---------------------------------------------------------------------------
// K2: per (b, scale, site) attention + channel-mix. (unchanged, validated)
// ---------------------------------------------------------------------------
__global__ __launch_bounds__(256) void site_kernel(
    const float* __restrict__ pool16,
    const float* __restrict__ cw0, const float* __restrict__ cw1,
    const float* __restrict__ cw2,
    const float* __restrict__ sw0, const float* __restrict__ sw1,
    const float* __restrict__ sw2,
    const float* __restrict__ fusion_w,
    float* __restrict__ y4, float* __restrict__ y8, float* __restrict__ y16) {

    __shared__ float P[256];
    __shared__ float Wm[961];
    __shared__ float QKV[279];
    __shared__ float QW[93];
    __shared__ float A[9];
    __shared__ float OUTV[93];

    int t = threadIdx.x;
    int blk = blockIdx.x;
    int b = blk / 336;
    int r = blk % 336;

    int s, site, foff;
    const float* cw; const float* sw; float* yout;
    if (r < 256)      { s = 16; site = r;       cw = cw2; sw = sw2; foff = 186; yout = y16; }
    else if (r < 320) { s = 8;  site = r - 256; cw = cw1; sw = sw1; foff = 93;  yout = y8;  }
    else              { s = 4;  site = r - 320; cw = cw0; sw = sw0; foff = 0;   yout = y4;  }
    int i = site / s, j = site % s;

    for (int idx = t; idx < 961; idx += 256) Wm[idx] = sw[idx];

    {
        int f = 16 / s;
        float acc = 0.f;
        int base = (b * 256 + t) * 256;
        for (int ii = 0; ii < f; ++ii)
            for (int jj = 0; jj < f; ++jj)
                acc += pool16[base + (i * f + ii) * 16 + (j * f + jj)];
        P[t] = acc / (float)(f * f);
    }
    __syncthreads();

    for (int o = t; o < 279; o += 256) {
        const float4* wrow = (const float4*)(cw + o * 256);
        float acc = 0.f;
#pragma unroll 8
        for (int c4 = 0; c4 < 64; ++c4) {
            float4 wv = wrow[c4];
            acc += wv.x * P[c4 * 4] + wv.y * P[c4 * 4 + 1] +
                   wv.z * P[c4 * 4 + 2] + wv.w * P[c4 * 4 + 3];
        }
        QKV[o] = acc;
    }
    __syncthreads();

    if (t < 93) {
        int g = t / 31, m = t % 31;
        float acc = 0.f;
        for (int n = 0; n < 31; ++n) acc += QKV[g * 31 + n] * Wm[n * 31 + m];
        QW[t] = acc;
    }
    __syncthreads();
    if (t < 9) {
        int g = t / 3, h = t % 3;
        float acc = 0.f;
        for (int m = 0; m < 31; ++m) acc += QW[g * 31 + m] * QKV[93 + h * 31 + m];
        A[t] = acc * 0.57735026918962576f;
    }
    __syncthreads();
    if (t < 3) {
        float a0 = A[t * 3], a1 = A[t * 3 + 1], a2 = A[t * 3 + 2];
        float mx = fmaxf(a0, fmaxf(a1, a2));
        float e0 = expf(a0 - mx), e1 = expf(a1 - mx), e2 = expf(a2 - mx);
        float inv = 1.0f / (e0 + e1 + e2);
        A[t * 3] = e0 * inv; A[t * 3 + 1] = e1 * inv; A[t * 3 + 2] = e2 * inv;
    }
    __syncthreads();
    if (t < 93) {
        int g = t / 31, n = t % 31;
        OUTV[t] = A[g * 3] * QKV[186 + n] + A[g * 3 + 1] * QKV[186 + 31 + n] +
                  A[g * 3 + 2] * QKV[186 + 62 + n];
    }
    __syncthreads();
    {
        const float* fr = fusion_w + t * 279 + foff;
        float acc = 0.f;
#pragma unroll 31
        for (int c = 0; c < 93; ++c) acc += fr[c] * OUTV[c];
        yout[(size_t)(b * 256 + t) * (s * s) + site] = acc;
    }
}

// ---------------------------------------------------------------------------
// K3: per-CHANNEL stats (1024 blocks; validated rounds 9-15).
// ---------------------------------------------------------------------------
__global__ __launch_bounds__(256) void chanstat_kernel(
    const float* __restrict__ y4, const float* __restrict__ y8,
    const float* __restrict__ y16,
    const float* __restrict__ xp4, const float* __restrict__ xp8,
    const float* __restrict__ xp16,
    const float* __restrict__ sx, const float* __restrict__ fusion_b,
    double* __restrict__ chanS) {

    __shared__ float G1616[256], G168[128], G164[64], G88[64], G84[32], G44[16];
    __shared__ float cs[28];
    __shared__ float ybuf[336], xbuf[336];
    __shared__ float Tm[256];
    __shared__ float red[8];

    int t = threadIdx.x;
    int bc = blockIdx.x;          // b*256 + c

    for (int e = t; e < 588; e += 256) {
        if (e >= 560) {
            int q = e - 560; int sC, iC;
            if (q < 16) { sC = 16; iC = q; }
            else if (q < 24) { sC = 8; iC = q - 16; }
            else { sC = 4; iC = q - 24; }
            int R = 256 / sC;
            int lo = max(0, R * iC - R / 2), hi = min(256, R * iC + (3 * R) / 2);
            float Rinv = 1.f / (float)R, smax = (float)(sC - 1);
            float a = 0.f;
            for (int h = lo; h < hi; ++h) {
                float src = fminf(fmaxf(((float)h + 0.5f) * Rinv - 0.5f, 0.f), smax);
                int lq = (int)src; float fr = src - (float)lq;
                a += (iC == lq) ? (1.f - fr) : ((iC == lq + 1) ? fr : 0.f);
            }
            cs[q] = a;
            continue;
        }
        int sA, sB, iA, iB; float* dst; int off;
        if (e < 256)      { sA = 16; sB = 16; iA = e >> 4; iB = e & 15; dst = G1616; off = e; }
        else if (e < 384) { int q = e - 256; sA = 16; sB = 8; iA = q >> 3; iB = q & 7; dst = G168; off = q; }
        else if (e < 448) { int q = e - 384; sA = 16; sB = 4; iA = q >> 2; iB = q & 3; dst = G164; off = q; }
        else if (e < 512) { int q = e - 448; sA = 8;  sB = 8; iA = q >> 3; iB = q & 7; dst = G88;  off = q; }
        else if (e < 544) { int q = e - 512; sA = 8;  sB = 4; iA = q >> 2; iB = q & 3; dst = G84;  off = q; }
        else              { int q = e - 544; sA = 4;  sB = 4; iA = q >> 2; iB = q & 3; dst = G44;  off = q; }
        int RA = 256 / sA, RB = 256 / sB;
        int lo = max(max(0, RA * iA - RA / 2), RB * iB - RB / 2);
        int hi = min(min(256, RA * iA + (3 * RA) / 2), RB * iB + (3 * RB) / 2);
        float RAi = 1.f / (float)RA, RBi = 1.f / (float)RB;
        float smA = (float)(sA - 1), smB = (float)(sB - 1);
        float a = 0.f;
        for (int h = lo; h < hi; ++h) {
            float sa = fminf(fmaxf(((float)h + 0.5f) * RAi - 0.5f, 0.f), smA);
            int la = (int)sa; float fa = sa - (float)la;
            float wa = (iA == la) ? (1.f - fa) : ((iA == la + 1) ? fa : 0.f);
            float sb = fminf(fmaxf(((float)h + 0.5f) * RBi - 0.5f, 0.f), smB);
            int lb = (int)sb; float fb_ = sb - (float)lb;
            float wb = (iB == lb) ? (1.f - fb_) : ((iB == lb + 1) ? fb_ : 0.f);
            a += wa * wb;
        }
        dst[off] = a;
    }

    size_t bcs = (size_t)bc;
    ybuf[t] = y16[bcs * 256 + t];
    xbuf[t] = xp16[bcs * 256 + t];
    if (t < 64) { ybuf[256 + t] = y8[bcs * 64 + t]; xbuf[256 + t] = xp8[bcs * 64 + t]; }
    else if (t < 80) { ybuf[256 + t] = y4[bcs * 16 + (t - 64)]; xbuf[256 + t] = xp4[bcs * 16 + (t - 64)]; }
    __syncthreads();

    float pu = 0.f, pv = 0.f;
    for (int e = t; e < 336; e += 256) {
        float yv = ybuf[e];
        pv += 2.f * yv * xbuf[e];
        int ci, cj;
        if (e < 256)      { ci = e >> 4;               cj = e & 15; }
        else if (e < 320) { ci = 16 + ((e - 256) >> 3); cj = 16 + ((e - 256) & 7); }
        else              { ci = 24 + ((e - 320) >> 2); cj = 24 + ((e - 320) & 3); }
        pu += yv * cs[ci] * cs[cj];
    }

    for (int p = 0; p < 6; ++p) {
        const float* Gp; int sA, sB, yAoff, yBoff; float factor;
        switch (p) {
            case 0: Gp = G1616; sA = 16; sB = 16; yAoff = 0;   yBoff = 0;   factor = 1.f; break;
            case 1: Gp = G168;  sA = 16; sB = 8;  yAoff = 0;   yBoff = 256; factor = 2.f; break;
            case 2: Gp = G164;  sA = 16; sB = 4;  yAoff = 0;   yBoff = 320; factor = 2.f; break;
            case 3: Gp = G88;   sA = 8;  sB = 8;  yAoff = 256; yBoff = 256; factor = 1.f; break;
            case 4: Gp = G84;   sA = 8;  sB = 4;  yAoff = 256; yBoff = 320; factor = 2.f; break;
            default:Gp = G44;   sA = 4;  sB = 4;  yAoff = 320; yBoff = 320; factor = 1.f; break;
        }
        __syncthreads();
        int nT = sB * sA;
        if (t < nT) {
            int iB = t / sA, jA = t - iB * sA;
            float a = 0.f;
            for (int jB = 0; jB < sB; ++jB)
                a += Gp[jA * sB + jB] * ybuf[yBoff + iB * sB + jB];
            Tm[t] = a;
        }
        __syncthreads();
        int nB = sA * sA;
        if (t < nB) {
            int iA = t / sA, jA = t - iA * sA;
            float a = 0.f;
            for (int iB = 0; iB < sB; ++iB)
                a += Gp[iA * sB + iB] * Tm[iB * sA + jA];
            pv += factor * ybuf[yAoff + t] * a;
        }
    }

#pragma unroll
    for (int off = 1; off < 64; off <<= 1) {
        pu += __shfl_xor(pu, off);
        pv += __shfl_xor(pv, off);
    }
    __syncthreads();
    if ((t & 63) == 0) { red[(t >> 6) * 2] = pu; red[(t >> 6) * 2 + 1] = pv; }
    __syncthreads();
    if (t == 0) {
        float puT = red[0] + red[2] + red[4] + red[6];
        float pvT = red[1] + red[3] + red[5] + red[7];
        float fb = fusion_b[bc & 255];
        float s1 = sx[bc * 2], s2 = sx[bc * 2 + 1];
        double S1 = (double)s1 + 65536.0 * (double)fb + (double)puT;
        double S2 = (double)s2 + 2.0 * (double)fb * (double)s1 +
                    65536.0 * (double)fb * (double)fb +
                    2.0 * (double)fb * (double)puT + (double)pvT;
        chanS[bc * 2] = S1;
        chanS[bc * 2 + 1] = S2;
    }
}

// ---------------------------------------------------------------------------
// K4: fold 8 channels -> per-(b,g) mean/rstd. One block, 128 threads.
// ---------------------------------------------------------------------------
__global__ __launch_bounds__(128) void gnfold_kernel(
    const double* __restrict__ chanS, float* __restrict__ stats_g) {
    int t = threadIdx.x;            // b*32 + g
    int b = t >> 5, g = t & 31;
    double gS1 = 0.0, gS2 = 0.0;
    for (int c8 = 0; c8 < 8; ++c8) {
        int c = g * 8 + c8;
        gS1 += chanS[(b * 256 + c) * 2];
        gS2 += chanS[(b * 256 + c) * 2 + 1];
    }
    double mean = gS1 / 524288.0;
    double var  = gS2 / 524288.0 - mean * mean;
    stats_g[t * 2] = (float)mean;
    stats_g[t * 2 + 1] = (float)(1.0 / sqrt(var + 1e-5));
}

// ---------------------------------------------------------------------------
// K5: final pass — round-14 reversed-order version (unchanged). This round it
// is launched 3x total (2 extra TIMING PROBES writing identical data to out;
// deterministic). D_w = (dur_us - 254.4)/2.
// ---------------------------------------------------------------------------
__global__ __launch_bounds__(256) void write_kernel(
    const float* __restrict__ x,
    const float* __restrict__ ws_y4, const float* __restrict__ ws_y8,
    const float* __restrict__ ws_y16,
    const float* __restrict__ fusion_b,
    const float* __restrict__ gn_w, const float* __restrict__ gn_b,
    const float* __restrict__ stats_g,
    float* __restrict__ out) {

    __shared__ float ly16[256], ly8[64], ly4[16];
    __shared__ float2 rbd16[16][16];
    __shared__ float2 rbd8[16][8];
    __shared__ float2 rbd4[16][4];

    int blk = (B * C * 16 - 1) - blockIdx.x;   // reversed: L3 ping-pong
    int hblk = blk & 15;
    int c = (blk >> 4) & 255;
    int b = blk >> 12;
    int t = threadIdx.x;

    ly16[t] = ws_y16[(size_t)(b * 256 + c) * 256 + t];
    if (t < 64) ly8[t] = ws_y8[(size_t)(b * 256 + c) * 64 + t];
    if (t < 16) ly4[t] = ws_y4[(size_t)(b * 256 + c) * 16 + t];
    __syncthreads();

    for (int idx = t; idx < 448; idx += 256) {
        int r = idx / 28;
        int q = idx - r * 28;
        int h = hblk * 16 + r;
        if (q < 16) {
            float src = (h + 0.5f) * 0.0625f - 0.5f;
            src = fminf(fmaxf(src, 0.f), 15.f);
            int lo = (int)src; float wf = src - lo; int hi = min(lo + 1, 15);
            float rb = (1.f - wf) * ly16[lo * 16 + q] + wf * ly16[hi * 16 + q];
            rbd16[r][q].x = rb;
            if (q > 0) rbd16[r][q - 1].y = rb;
            if (q == 15) rbd16[r][15].y = rb;
        } else if (q < 24) {
            int jj = q - 16;
            float src = (h + 0.5f) * 0.03125f - 0.5f;
            src = fminf(fmaxf(src, 0.f), 7.f);
            int lo = (int)src; float wf = src - lo; int hi = min(lo + 1, 7);
            float rb = (1.f - wf) * ly8[lo * 8 + jj] + wf * ly8[hi * 8 + jj];
            rbd8[r][jj].x = rb;
            if (jj > 0) rbd8[r][jj - 1].y = rb;
            if (jj == 7) rbd8[r][7].y = rb;
        } else {
            int jj = q - 24;
            float src = (h + 0.5f) * 0.015625f - 0.5f;
            src = fminf(fmaxf(src, 0.f), 3.f);
            int lo = (int)src; float wf = src - lo; int hi = min(lo + 1, 3);
            float rb = (1.f - wf) * ly4[lo * 4 + jj] + wf * ly4[hi * 4 + jj];
            rbd4[r][jj].x = rb;
            if (jj > 0) rbd4[r][jj - 1].y = rb;
            if (jj == 3) rbd4[r][3].y = rb;
        }
    }
    __syncthreads();

    int w4 = t & 63;
    int wg = t >> 6;
    int w0 = w4 * 4;

    int jlo16[4], jlo8[4], jlo4[4];
    float ww16[4], ww8[4], ww4[4];
#pragma unroll
    for (int p = 0; p < 4; ++p) {
        int w = w0 + p;
        float s16 = fminf(fmaxf((w + 0.5f) * 0.0625f - 0.5f, 0.f), 15.f);
        jlo16[p] = (int)s16; ww16[p] = s16 - jlo16[p];
        float s8 = fminf(fmaxf((w + 0.5f) * 0.03125f - 0.5f, 0.f), 7.f);
        jlo8[p] = (int)s8; ww8[p] = s8 - jlo8[p];
        float s4 = fminf(fmaxf((w + 0.5f) * 0.015625f - 0.5f, 0.f), 3.f);
        jlo4[p] = (int)s4; ww4[p] = s4 - jlo4[p];
    }

    float fb_c = fusion_b[c];
    int gidx = c >> 3;
    float mean = stats_g[(b * 32 + gidx) * 2];
    float rstd = stats_g[(b * 32 + gidx) * 2 + 1];
    float gwc = gn_w[c], gbc = gn_b[c];

    const float4* xp = (const float4*)(x + (size_t)(b * 256 + c) * (H * Wd));
    float4* op = (float4*)(out + (size_t)(b * 256 + c) * (H * Wd));

#pragma unroll
    for (int it = 0; it < 4; ++it) {
        int r = it * 4 + wg;
        int idx4 = (hblk * 16 + r) * 64 + w4;
        float4 xv = xp[idx4];
        float res[4];
        float px[4] = {xv.x, xv.y, xv.z, xv.w};
#pragma unroll
        for (int p = 0; p < 4; ++p) {
            float f = fb_c;
            float2 v16 = rbd16[r][jlo16[p]];
            f += (1.f - ww16[p]) * v16.x + ww16[p] * v16.y;
            float2 v8 = rbd8[r][jlo8[p]];
            f += (1.f - ww8[p]) * v8.x + ww8[p] * v8.y;
            float2 v4 = rbd4[r][jlo4[p]];
            f += (1.f - ww4[p]) * v4.x + ww4[p] * v4.y;
            float tv = px[p] + f;
            res[p] = (tv - mean) * rstd * gwc + gbc;
        }
        op[idx4] = make_float4(res[0], res[1], res[2], res[3]);
    }
}

// ---------------------------------------------------------------------------
extern "C" void kernel_launch(void* const* d_in, const int* in_sizes, int n_in,
                              void* d_out, int out_size, void* d_ws, size_t ws_size,
                              hipStream_t stream) {
    const float* x   = (const float*)d_in[0];
    const float* cw0 = (const float*)d_in[1];
    const float* cw1 = (const float*)d_in[2];
    const float* cw2 = (const float*)d_in[3];
    const float* sw0 = (const float*)d_in[4];
    const float* sw1 = (const float*)d_in[5];
    const float* sw2 = (const float*)d_in[6];
    const float* fw  = (const float*)d_in[7];
    const float* fb  = (const float*)d_in[8];
    const float* gw  = (const float*)d_in[9];
    const float* gb  = (const float*)d_in[10];
    float* out = (float*)d_out;

    float* ws     = (float*)d_ws;
    float* pool16 = ws;                    // 262144
    float* y4     = pool16 + 262144;       // 16384
    float* y8     = y4 + 16384;            // 65536
    float* y16    = y8 + 65536;            // 262144
    float* xp16   = y16 + 262144;          // 262144
    float* xp8    = xp16 + 262144;         // 65536
    float* xp4    = xp8 + 65536;           // 16384
    float* sx     = xp4 + 16384;           // 2048
    float* statsg = sx + 2048;             // 256
    double* chanS = (double*)(statsg + 256);  // 2048 doubles

    xreadproj_kernel<<<B * C, 256, 0, stream>>>(x, pool16, xp16, xp8, xp4, sx);
    site_kernel<<<B * 336, 256, 0, stream>>>(pool16, cw0, cw1, cw2,
                                             sw0, sw1, sw2, fw, y4, y8, y16);
    chanstat_kernel<<<B * C, 256, 0, stream>>>(y4, y8, y16, xp4, xp8, xp16,
                                               sx, fb, chanS);
    gnfold_kernel<<<1, 128, 0, stream>>>(chanS, statsg);
    // --- timing probes: 2 extra instances writing identical data to out ---
    write_kernel<<<B * C * 16, 256, 0, stream>>>(x, y4, y8, y16, fb, gw, gb,
                                                 statsg, out);
    write_kernel<<<B * C * 16, 256, 0, stream>>>(x, y4, y8, y16, fb, gw, gb,
                                                 statsg, out);
    write_kernel<<<B * C * 16, 256, 0, stream>>>(x, y4, y8, y16, fb, gw, gb,
                                                 statsg, out);
}

// Round 17
// 237.959 us; speedup vs baseline: 1.9139x; 1.9139x over previous
//
#include <hip/hip_runtime.h>
#include <hip/hip_bf16.h>
#include <math.h>

#define B 4
#define C 256
#define H 256
#define Wd 256

// ---------------------------------------------------------------------------
// K1: plane-per-block streaming pass (measured 52.4 us, ~81% of achievable BW;
// unchanged) + NEW hidden tail: blocks bc<588 compute one Gram/cs entry each
// (64-lane parallel h-loop + shuffle reduce, ~0.1 us, hidden) into gram[].
// ---------------------------------------------------------------------------
__global__ __launch_bounds__(256) void xreadproj_kernel(
    const float* __restrict__ x,
    float* __restrict__ pool16, float* __restrict__ xp16o,
    float* __restrict__ xp8o, float* __restrict__ xp4o,
    float* __restrict__ sx, float* __restrict__ gram) {

    __shared__ float P0[16][72];    // p0; guards [64..71]=0
    __shared__ float SS16[16][68];  // [2+l]=S16; guards [0..1],[66..67]=0
    __shared__ float SS8[16][72];   // [4+l]=S8;  guards [0..3],[68..71]=0
    __shared__ float SS4[16][80];   // [8+l]=S4;  guards [0..7],[72..79]=0
    __shared__ float Rs[16 * 29];   // per-slab rowproj, padded stride 29
    __shared__ float rs[4][2];

    int bc = blockIdx.x;
    int t = threadIdx.x;
    int wg = t >> 6, l = t & 63;

    const float4* xp = (const float4*)(x + (size_t)bc * (H * Wd));

    // guard zeros (36 per row; persist across slabs)
    for (int e = t; e < 576; e += 256) {
        int r = e / 36, g = e - r * 36;
        if (g < 8)       P0[r][64 + g] = 0.f;
        else if (g < 10) SS16[r][g - 8] = 0.f;
        else if (g < 12) SS16[r][56 + g] = 0.f;        // 66,67
        else if (g < 16) SS8[r][g - 12] = 0.f;
        else if (g < 20) SS8[r][52 + g] = 0.f;         // 68..71
        else if (g < 28) SS4[r][g - 20] = 0.f;
        else             SS4[r][44 + g] = 0.f;         // 72..79
    }

    // per-lane w-side constants (validated)
    float a16, b16, a8, b8, a4, b4;
    {
        float w0 = 4.f * (float)l + 0.5f;
        float s16v = w0 * 0.0625f - 0.5f;
        if (l <= 1 || l >= 62) { a16 = 0.f; b16 = 0.f; }
        else { a16 = s16v - floorf(s16v); b16 = 0.0625f; }
        float s8v = w0 * 0.03125f - 0.5f;
        if (l <= 3 || l >= 60) { a8 = 0.f; b8 = 0.f; }
        else { a8 = s8v - floorf(s8v); b8 = 0.03125f; }
        float s4v = w0 * 0.015625f - 0.5f;
        if (l <= 7 || l >= 56) { a4 = 0.f; b4 = 0.f; }
        else { a4 = s4v - floorf(s4v); b4 = 0.015625f; }
    }

    // fold-owner indices
    const int i16 = t >> 4, j16 = t & 15;
    const int i8 = t >> 3, j8 = t & 7;              // valid for t<64
    const int i4 = (t - 64) >> 2, j4 = (t - 64) & 3; // valid for 64<=t<80

    float accA = 0.f;   // xp16 entry
    float accB = 0.f;   // xp8 (t<64) or xp4 (64<=t<80)
    float sx1 = 0.f, sx2 = 0.f;

    float4 v[4], vn[4];
#pragma unroll
    for (int it = 0; it < 4; ++it)
        v[it] = xp[(wg * 4 + it) * 64 + l];

#pragma unroll 1
    for (int k = 0; k < 16; ++k) {
        // ---- fold slab k-1 from Rs (validated windows; ascending r) ----
        if (k > 0) {
            int kk = k - 1;
            if (kk >= i16 - 1 && kk <= i16 + 1) {
#pragma unroll
                for (int rl = 0; rl < 16; ++rl) {
                    float src = ((float)(kk * 16 + rl) + 0.5f) * 0.0625f - 0.5f;
                    src = fminf(fmaxf(src, 0.f), 15.f);
                    int lo = (int)src; float fr = src - (float)lo;
                    float w = (i16 == lo) ? (1.f - fr) : ((i16 == lo + 1) ? fr : 0.f);
                    accA += w * Rs[rl * 29 + j16];
                }
            }
            if (t < 64) {
                if (kk >= 2 * i8 - 1 && kk <= 2 * i8 + 2) {
#pragma unroll
                    for (int rl = 0; rl < 16; ++rl) {
                        float src = ((float)(kk * 16 + rl) + 0.5f) * 0.03125f - 0.5f;
                        src = fminf(fmaxf(src, 0.f), 7.f);
                        int lo = (int)src; float fr = src - (float)lo;
                        float w = (i8 == lo) ? (1.f - fr) : ((i8 == lo + 1) ? fr : 0.f);
                        accB += w * Rs[rl * 29 + 16 + j8];
                    }
                }
            } else if (t < 80) {
                if (kk >= 4 * i4 - 2 && kk <= 4 * i4 + 5) {
#pragma unroll
                    for (int rl = 0; rl < 16; ++rl) {
                        float src = ((float)(kk * 16 + rl) + 0.5f) * 0.015625f - 0.5f;
                        src = fminf(fmaxf(src, 0.f), 3.f);
                        int lo = (int)src; float fr = src - (float)lo;
                        float w = (i4 == lo) ? (1.f - fr) : ((i4 == lo + 1) ? fr : 0.f);
                        accB += w * Rs[rl * 29 + 24 + j4];
                    }
                }
            }
        }

        // ---- stage slab k (P0/S only) + sx ----
#pragma unroll
        for (int it = 0; it < 4; ++it) {
            int r = wg * 4 + it;
            float4 vv = v[it];
            float p0 = (vv.x + vv.y) + (vv.z + vv.w);
            float pw = fmaf(3.f, vv.w, fmaf(2.f, vv.z, vv.y));
            sx1 += p0;
            sx2 += vv.x * vv.x + vv.y * vv.y + vv.z * vv.z + vv.w * vv.w;
            P0[r][l]       = p0;
            SS16[r][2 + l] = fmaf(b16, pw, a16 * p0);
            SS8[r][4 + l]  = fmaf(b8,  pw, a8  * p0);
            SS4[r][8 + l]  = fmaf(b4,  pw, a4  * p0);
        }
        __syncthreads();     // barrier A

        // ---- prefetch slab k+1 (after barrier A) ----
        if (k < 15) {
#pragma unroll
            for (int it = 0; it < 4; ++it)
                vn[it] = xp[((k + 1) * 16 + wg * 4 + it) * 64 + l];
        }

        // ---- merge slab k: staging -> Rs + pool16 (validated sums) ----
        for (int tk = t; tk < 464; tk += 256) {
            if (tk < 256) {                       // s16
                int r = tk >> 4, j = tk & 15;
                float sum = 0.f;
#pragma unroll
                for (int q = 0; q < 4; ++q)
                    sum += P0[r][4 * j + 2 + q] - SS16[r][4 * j + 4 + q];
#pragma unroll
                for (int q = 0; q < 4; ++q) sum += SS16[r][4 * j + q];
                if (j == 0) sum += (P0[r][0] - SS16[r][2]) + (P0[r][1] - SS16[r][3]);
                Rs[r * 29 + j] = sum;
            } else if (tk < 384) {                // s8
                int q2 = tk - 256; int r = q2 >> 3, j = q2 & 7;
                float sum = 0.f;
#pragma unroll
                for (int q = 0; q < 8; ++q)
                    sum += P0[r][8 * j + 4 + q] - SS8[r][8 * j + 8 + q];
#pragma unroll
                for (int q = 0; q < 8; ++q) sum += SS8[r][8 * j + q];
                if (j == 0) {
#pragma unroll
                    for (int q = 0; q < 4; ++q) sum += P0[r][q] - SS8[r][4 + q];
                }
                Rs[r * 29 + 16 + j] = sum;
            } else if (tk < 448) {                // s4
                int q2 = tk - 384; int r = q2 >> 2, j = q2 & 3;
                float sum = 0.f;
#pragma unroll
                for (int q = 0; q < 16; ++q)
                    sum += P0[r][16 * j + 8 + q] - SS4[r][16 * j + 16 + q];
#pragma unroll
                for (int q = 0; q < 16; ++q) sum += SS4[r][16 * j + q];
                if (j == 0) {
#pragma unroll
                    for (int q = 0; q < 8; ++q) sum += P0[r][q] - SS4[r][8 + q];
                }
                Rs[r * 29 + 24 + j] = sum;
            } else {                              // pool row
                int j = tk - 448;
                float sum = 0.f;
#pragma unroll
                for (int r2 = 0; r2 < 16; ++r2) {
#pragma unroll
                    for (int q = 0; q < 4; ++q) sum += P0[r2][4 * j + q];
                }
                pool16[(size_t)bc * 256 + k * 16 + j] = sum * (1.f / 256.f);
            }
        }
        __syncthreads();     // barrier B
#pragma unroll
        for (int it = 0; it < 4; ++it) v[it] = vn[it];
    }

    // ---- fold last slab (15) ----
    {
        int kk = 15;
        if (kk >= i16 - 1 && kk <= i16 + 1) {
#pragma unroll
            for (int rl = 0; rl < 16; ++rl) {
                float src = ((float)(kk * 16 + rl) + 0.5f) * 0.0625f - 0.5f;
                src = fminf(fmaxf(src, 0.f), 15.f);
                int lo = (int)src; float fr = src - (float)lo;
                float w = (i16 == lo) ? (1.f - fr) : ((i16 == lo + 1) ? fr : 0.f);
                accA += w * Rs[rl * 29 + j16];
            }
        }
        if (t < 64) {
            if (kk >= 2 * i8 - 1 && kk <= 2 * i8 + 2) {
#pragma unroll
                for (int rl = 0; rl < 16; ++rl) {
                    float src = ((float)(kk * 16 + rl) + 0.5f) * 0.03125f - 0.5f;
                    src = fminf(fmaxf(src, 0.f), 7.f);
                    int lo = (int)src; float fr = src - (float)lo;
                    float w = (i8 == lo) ? (1.f - fr) : ((i8 == lo + 1) ? fr : 0.f);
                    accB += w * Rs[rl * 29 + 16 + j8];
                }
            }
        } else if (t < 80) {
            if (kk >= 4 * i4 - 2 && kk <= 4 * i4 + 5) {
#pragma unroll
                for (int rl = 0; rl < 16; ++rl) {
                    float src = ((float)(kk * 16 + rl) + 0.5f) * 0.015625f - 0.5f;
                    src = fminf(fmaxf(src, 0.f), 3.f);
                    int lo = (int)src; float fr = src - (float)lo;
                    float w = (i4 == lo) ? (1.f - fr) : ((i4 == lo + 1) ? fr : 0.f);
                    accB += w * Rs[rl * 29 + 24 + j4];
                }
            }
        }
    }

    xp16o[(size_t)bc * 256 + t] = accA;
    if (t < 64) xp8o[(size_t)bc * 64 + t] = accB;
    else if (t < 80) xp4o[(size_t)bc * 16 + (t - 64)] = accB;

    // sx: wave reduce (validated pattern)
#pragma unroll
    for (int off = 1; off < 64; off <<= 1) {
        sx1 += __shfl_xor(sx1, off);
        sx2 += __shfl_xor(sx2, off);
    }
    if (l == 0) { rs[wg][0] = sx1; rs[wg][1] = sx2; }
    __syncthreads();
    if (t == 0) {
        sx[bc * 2]     = rs[0][0] + rs[1][0] + rs[2][0] + rs[3][0];
        sx[bc * 2 + 1] = rs[0][1] + rs[1][1] + rs[2][1] + rs[3][1];
    }

    // ---- Gram/cs precompute tail: block bc<588 computes entry bc (wave 0) --
    if (bc < 588 && t < 64) {
        int e = bc;
        float acc = 0.f;
        if (e >= 560) {                 // column sums
            int q = e - 560; int sC, iC;
            if (q < 16) { sC = 16; iC = q; }
            else if (q < 24) { sC = 8; iC = q - 16; }
            else { sC = 4; iC = q - 24; }
            int R = 256 / sC;
            int lo = max(0, R * iC - R / 2), hi = min(256, R * iC + (3 * R) / 2);
            float Rinv = 1.f / (float)R, smax = (float)(sC - 1);
            for (int h = lo + t; h < hi; h += 64) {
                float src = fminf(fmaxf(((float)h + 0.5f) * Rinv - 0.5f, 0.f), smax);
                int lq = (int)src; float fr = src - (float)lq;
                acc += (iC == lq) ? (1.f - fr) : ((iC == lq + 1) ? fr : 0.f);
            }
        } else {                        // Gram entries
            int sA, sB, iA, iB;
            if (e < 256)      { sA = 16; sB = 16; iA = e >> 4; iB = e & 15; }
            else if (e < 384) { int q = e - 256; sA = 16; sB = 8; iA = q >> 3; iB = q & 7; }
            else if (e < 448) { int q = e - 384; sA = 16; sB = 4; iA = q >> 2; iB = q & 3; }
            else if (e < 512) { int q = e - 448; sA = 8;  sB = 8; iA = q >> 3; iB = q & 7; }
            else if (e < 544) { int q = e - 512; sA = 8;  sB = 4; iA = q >> 2; iB = q & 3; }
            else              { int q = e - 544; sA = 4;  sB = 4; iA = q >> 2; iB = q & 3; }
            int RA = 256 / sA, RB = 256 / sB;
            int lo = max(max(0, RA * iA - RA / 2), RB * iB - RB / 2);
            int hi = min(min(256, RA * iA + (3 * RA) / 2), RB * iB + (3 * RB) / 2);
            float RAi = 1.f / (float)RA, RBi = 1.f / (float)RB;
            float smA = (float)(sA - 1), smB = (float)(sB - 1);
            for (int h = lo + t; h < hi; h += 64) {
                float sa = fminf(fmaxf(((float)h + 0.5f) * RAi - 0.5f, 0.f), smA);
                int la = (int)sa; float fa = sa - (float)la;
                float wa = (iA == la) ? (1.f - fa) : ((iA == la + 1) ? fa : 0.f);
                float sb = fminf(fmaxf(((float)h + 0.5f) * RBi - 0.5f, 0.f), smB);
                int lb = (int)sb; float fb_ = sb - (float)lb;
                float wb = (iB == lb) ? (1.f - fb_) : ((iB == lb + 1) ? fb_ : 0.f);
                acc += wa * wb;
            }
        }
#pragma unroll
        for (int off = 1; off < 64; off <<= 1) acc += __shfl_xor(acc, off);
        if (t == 0) gram[e] = acc;
    }
}

// ---------------------------------------------------------------------------
// K2: per (b, scale, site) attention + channel-mix. (unchanged, validated)
// ---------------------------------------------------------------------------
__global__ __launch_bounds__(256) void site_kernel(
    const float* __restrict__ pool16,
    const float* __restrict__ cw0, const float* __restrict__ cw1,
    const float* __restrict__ cw2,
    const float* __restrict__ sw0, const float* __restrict__ sw1,
    const float* __restrict__ sw2,
    const float* __restrict__ fusion_w,
    float* __restrict__ y4, float* __restrict__ y8, float* __restrict__ y16) {

    __shared__ float P[256];
    __shared__ float Wm[961];
    __shared__ float QKV[279];
    __shared__ float QW[93];
    __shared__ float A[9];
    __shared__ float OUTV[93];

    int t = threadIdx.x;
    int blk = blockIdx.x;
    int b = blk / 336;
    int r = blk % 336;

    int s, site, foff;
    const float* cw; const float* sw; float* yout;
    if (r < 256)      { s = 16; site = r;       cw = cw2; sw = sw2; foff = 186; yout = y16; }
    else if (r < 320) { s = 8;  site = r - 256; cw = cw1; sw = sw1; foff = 93;  yout = y8;  }
    else              { s = 4;  site = r - 320; cw = cw0; sw = sw0; foff = 0;   yout = y4;  }
    int i = site / s, j = site % s;

    for (int idx = t; idx < 961; idx += 256) Wm[idx] = sw[idx];

    {
        int f = 16 / s;
        float acc = 0.f;
        int base = (b * 256 + t) * 256;
        for (int ii = 0; ii < f; ++ii)
            for (int jj = 0; jj < f; ++jj)
                acc += pool16[base + (i * f + ii) * 16 + (j * f + jj)];
        P[t] = acc / (float)(f * f);
    }
    __syncthreads();

    for (int o = t; o < 279; o += 256) {
        const float4* wrow = (const float4*)(cw + o * 256);
        float acc = 0.f;
#pragma unroll 8
        for (int c4 = 0; c4 < 64; ++c4) {
            float4 wv = wrow[c4];
            acc += wv.x * P[c4 * 4] + wv.y * P[c4 * 4 + 1] +
                   wv.z * P[c4 * 4 + 2] + wv.w * P[c4 * 4 + 3];
        }
        QKV[o] = acc;
    }
    __syncthreads();

    if (t < 93) {
        int g = t / 31, m = t % 31;
        float acc = 0.f;
        for (int n = 0; n < 31; ++n) acc += QKV[g * 31 + n] * Wm[n * 31 + m];
        QW[t] = acc;
    }
    __syncthreads();
    if (t < 9) {
        int g = t / 3, h = t % 3;
        float acc = 0.f;
        for (int m = 0; m < 31; ++m) acc += QW[g * 31 + m] * QKV[93 + h * 31 + m];
        A[t] = acc * 0.57735026918962576f;
    }
    __syncthreads();
    if (t < 3) {
        float a0 = A[t * 3], a1 = A[t * 3 + 1], a2 = A[t * 3 + 2];
        float mx = fmaxf(a0, fmaxf(a1, a2));
        float e0 = expf(a0 - mx), e1 = expf(a1 - mx), e2 = expf(a2 - mx);
        float inv = 1.0f / (e0 + e1 + e2);
        A[t * 3] = e0 * inv; A[t * 3 + 1] = e1 * inv; A[t * 3 + 2] = e2 * inv;
    }
    __syncthreads();
    if (t < 93) {
        int g = t / 31, n = t % 31;
        OUTV[t] = A[g * 3] * QKV[186 + n] + A[g * 3 + 1] * QKV[186 + 31 + n] +
                  A[g * 3 + 2] * QKV[186 + 62 + n];
    }
    __syncthreads();
    {
        const float* fr = fusion_w + t * 279 + foff;
        float acc = 0.f;
#pragma unroll 31
        for (int c = 0; c < 93; ++c) acc += fr[c] * OUTV[c];
        yout[(size_t)(b * 256 + t) * (s * s) + site] = acc;
    }
}

// ---------------------------------------------------------------------------
// K3: per-CHANNEL stats (1024 blocks). Gram/cs now LOADED from gram[] (com-
// puted in xreadproj tail) instead of recomputed per block.
// ---------------------------------------------------------------------------
__global__ __launch_bounds__(256) void chanstat_kernel(
    const float* __restrict__ y4, const float* __restrict__ y8,
    const float* __restrict__ y16,
    const float* __restrict__ xp4, const float* __restrict__ xp8,
    const float* __restrict__ xp16,
    const float* __restrict__ sx, const float* __restrict__ fusion_b,
    const float* __restrict__ gram,
    double* __restrict__ chanS) {

    __shared__ float Gs[588];      // [0]=G1616, 256=G168, 384=G164, 448=G88,
                                   // 512=G84, 544=G44, 560=cs (decode offsets)
    __shared__ float ybuf[336], xbuf[336];
    __shared__ float Tm[256];
    __shared__ float red[8];

    int t = threadIdx.x;
    int bc = blockIdx.x;          // b*256 + c

    for (int e = t; e < 588; e += 256) Gs[e] = gram[e];

    const float* G1616 = Gs;
    const float* G168  = Gs + 256;
    const float* G164  = Gs + 384;
    const float* G88   = Gs + 448;
    const float* G84   = Gs + 512;
    const float* G44   = Gs + 544;
    const float* cs    = Gs + 560;

    size_t bcs = (size_t)bc;
    ybuf[t] = y16[bcs * 256 + t];
    xbuf[t] = xp16[bcs * 256 + t];
    if (t < 64) { ybuf[256 + t] = y8[bcs * 64 + t]; xbuf[256 + t] = xp8[bcs * 64 + t]; }
    else if (t < 80) { ybuf[256 + t] = y4[bcs * 16 + (t - 64)]; xbuf[256 + t] = xp4[bcs * 16 + (t - 64)]; }
    __syncthreads();

    float pu = 0.f, pv = 0.f;
    for (int e = t; e < 336; e += 256) {
        float yv = ybuf[e];
        pv += 2.f * yv * xbuf[e];
        int ci, cj;
        if (e < 256)      { ci = e >> 4;               cj = e & 15; }
        else if (e < 320) { ci = 16 + ((e - 256) >> 3); cj = 16 + ((e - 256) & 7); }
        else              { ci = 24 + ((e - 320) >> 2); cj = 24 + ((e - 320) & 3); }
        pu += yv * cs[ci] * cs[cj];
    }

    for (int p = 0; p < 6; ++p) {
        const float* Gp; int sA, sB, yAoff, yBoff; float factor;
        switch (p) {
            case 0: Gp = G1616; sA = 16; sB = 16; yAoff = 0;   yBoff = 0;   factor = 1.f; break;
            case 1: Gp = G168;  sA = 16; sB = 8;  yAoff = 0;   yBoff = 256; factor = 2.f; break;
            case 2: Gp = G164;  sA = 16; sB = 4;  yAoff = 0;   yBoff = 320; factor = 2.f; break;
            case 3: Gp = G88;   sA = 8;  sB = 8;  yAoff = 256; yBoff = 256; factor = 1.f; break;
            case 4: Gp = G84;   sA = 8;  sB = 4;  yAoff = 256; yBoff = 320; factor = 2.f; break;
            default:Gp = G44;   sA = 4;  sB = 4;  yAoff = 320; yBoff = 320; factor = 1.f; break;
        }
        __syncthreads();
        int nT = sB * sA;
        if (t < nT) {
            int iB = t / sA, jA = t - iB * sA;
            float a = 0.f;
            for (int jB = 0; jB < sB; ++jB)
                a += Gp[jA * sB + jB] * ybuf[yBoff + iB * sB + jB];
            Tm[t] = a;
        }
        __syncthreads();
        int nB = sA * sA;
        if (t < nB) {
            int iA = t / sA, jA = t - iA * sA;
            float a = 0.f;
            for (int iB = 0; iB < sB; ++iB)
                a += Gp[iA * sB + iB] * Tm[iB * sA + jA];
            pv += factor * ybuf[yAoff + t] * a;
        }
    }

#pragma unroll
    for (int off = 1; off < 64; off <<= 1) {
        pu += __shfl_xor(pu, off);
        pv += __shfl_xor(pv, off);
    }
    __syncthreads();
    if ((t & 63) == 0) { red[(t >> 6) * 2] = pu; red[(t >> 6) * 2 + 1] = pv; }
    __syncthreads();
    if (t == 0) {
        float puT = red[0] + red[2] + red[4] + red[6];
        float pvT = red[1] + red[3] + red[5] + red[7];
        float fb = fusion_b[bc & 255];
        float s1 = sx[bc * 2], s2 = sx[bc * 2 + 1];
        double S1 = (double)s1 + 65536.0 * (double)fb + (double)puT;
        double S2 = (double)s2 + 2.0 * (double)fb * (double)s1 +
                    65536.0 * (double)fb * (double)fb +
                    2.0 * (double)fb * (double)puT + (double)pvT;
        chanS[bc * 2] = S1;
        chanS[bc * 2 + 1] = S2;
    }
}

// ---------------------------------------------------------------------------
// K4: final pass (round-14 reversed-order math, unchanged) + NEW: computes its
// group's mean/rstd REDUNDANTLY from chanS (thread 0; identical arithmetic &
// order to the removed gnfold -> bit-identical, deterministic).
// ---------------------------------------------------------------------------
__global__ __launch_bounds__(256) void write_kernel(
    const float* __restrict__ x,
    const float* __restrict__ ws_y4, const float* __restrict__ ws_y8,
    const float* __restrict__ ws_y16,
    const float* __restrict__ fusion_b,
    const float* __restrict__ gn_w, const float* __restrict__ gn_b,
    const double* __restrict__ chanS,
    float* __restrict__ out) {

    __shared__ float ly16[256], ly8[64], ly4[16];
    __shared__ float2 rbd16[16][16];
    __shared__ float2 rbd8[16][8];
    __shared__ float2 rbd4[16][4];
    __shared__ float sstat[2];

    int blk = (B * C * 16 - 1) - blockIdx.x;   // reversed: L3 ping-pong
    int hblk = blk & 15;
    int c = (blk >> 4) & 255;
    int b = blk >> 12;
    int t = threadIdx.x;

    if (t == 0) {   // group stats from chanS (gnfold arithmetic, same order)
        int gidx = c >> 3;
        const double* cS = chanS + ((size_t)(b * 256 + gidx * 8)) * 2;
        double gS1 = 0.0, gS2 = 0.0;
#pragma unroll
        for (int c8 = 0; c8 < 8; ++c8) {
            gS1 += cS[c8 * 2];
            gS2 += cS[c8 * 2 + 1];
        }
        double meand = gS1 / 524288.0;
        double vard  = gS2 / 524288.0 - meand * meand;
        sstat[0] = (float)meand;
        sstat[1] = (float)(1.0 / sqrt(vard + 1e-5));
    }

    ly16[t] = ws_y16[(size_t)(b * 256 + c) * 256 + t];
    if (t < 64) ly8[t] = ws_y8[(size_t)(b * 256 + c) * 64 + t];
    if (t < 16) ly4[t] = ws_y4[(size_t)(b * 256 + c) * 16 + t];
    __syncthreads();

    for (int idx = t; idx < 448; idx += 256) {
        int r = idx / 28;
        int q = idx - r * 28;
        int h = hblk * 16 + r;
        if (q < 16) {
            float src = (h + 0.5f) * 0.0625f - 0.5f;
            src = fminf(fmaxf(src, 0.f), 15.f);
            int lo = (int)src; float wf = src - lo; int hi = min(lo + 1, 15);
            float rb = (1.f - wf) * ly16[lo * 16 + q] + wf * ly16[hi * 16 + q];
            rbd16[r][q].x = rb;
            if (q > 0) rbd16[r][q - 1].y = rb;
            if (q == 15) rbd16[r][15].y = rb;
        } else if (q < 24) {
            int jj = q - 16;
            float src = (h + 0.5f) * 0.03125f - 0.5f;
            src = fminf(fmaxf(src, 0.f), 7.f);
            int lo = (int)src; float wf = src - lo; int hi = min(lo + 1, 7);
            float rb = (1.f - wf) * ly8[lo * 8 + jj] + wf * ly8[hi * 8 + jj];
            rbd8[r][jj].x = rb;
            if (jj > 0) rbd8[r][jj - 1].y = rb;
            if (jj == 7) rbd8[r][7].y = rb;
        } else {
            int jj = q - 24;
            float src = (h + 0.5f) * 0.015625f - 0.5f;
            src = fminf(fmaxf(src, 0.f), 3.f);
            int lo = (int)src; float wf = src - lo; int hi = min(lo + 1, 3);
            float rb = (1.f - wf) * ly4[lo * 4 + jj] + wf * ly4[hi * 4 + jj];
            rbd4[r][jj].x = rb;
            if (jj > 0) rbd4[r][jj - 1].y = rb;
            if (jj == 3) rbd4[r][3].y = rb;
        }
    }
    __syncthreads();

    int w4 = t & 63;
    int wg = t >> 6;
    int w0 = w4 * 4;

    int jlo16[4], jlo8[4], jlo4[4];
    float ww16[4], ww8[4], ww4[4];
#pragma unroll
    for (int p = 0; p < 4; ++p) {
        int w = w0 + p;
        float s16 = fminf(fmaxf((w + 0.5f) * 0.0625f - 0.5f, 0.f), 15.f);
        jlo16[p] = (int)s16; ww16[p] = s16 - jlo16[p];
        float s8 = fminf(fmaxf((w + 0.5f) * 0.03125f - 0.5f, 0.f), 7.f);
        jlo8[p] = (int)s8; ww8[p] = s8 - jlo8[p];
        float s4 = fminf(fmaxf((w + 0.5f) * 0.015625f - 0.5f, 0.f), 3.f);
        jlo4[p] = (int)s4; ww4[p] = s4 - jlo4[p];
    }

    float fb_c = fusion_b[c];
    float mean = sstat[0];
    float rstd = sstat[1];
    float gwc = gn_w[c], gbc = gn_b[c];

    const float4* xp = (const float4*)(x + (size_t)(b * 256 + c) * (H * Wd));
    float4* op = (float4*)(out + (size_t)(b * 256 + c) * (H * Wd));

#pragma unroll
    for (int it = 0; it < 4; ++it) {
        int r = it * 4 + wg;
        int idx4 = (hblk * 16 + r) * 64 + w4;
        float4 xv = xp[idx4];
        float res[4];
        float px[4] = {xv.x, xv.y, xv.z, xv.w};
#pragma unroll
        for (int p = 0; p < 4; ++p) {
            float f = fb_c;
            float2 v16 = rbd16[r][jlo16[p]];
            f += (1.f - ww16[p]) * v16.x + ww16[p] * v16.y;
            float2 v8 = rbd8[r][jlo8[p]];
            f += (1.f - ww8[p]) * v8.x + ww8[p] * v8.y;
            float2 v4 = rbd4[r][jlo4[p]];
            f += (1.f - ww4[p]) * v4.x + ww4[p] * v4.y;
            float tv = px[p] + f;
            res[p] = (tv - mean) * rstd * gwc + gbc;
        }
        op[idx4] = make_float4(res[0], res[1], res[2], res[3]);
    }
}

// ---------------------------------------------------------------------------
extern "C" void kernel_launch(void* const* d_in, const int* in_sizes, int n_in,
                              void* d_out, int out_size, void* d_ws, size_t ws_size,
                              hipStream_t stream) {
    const float* x   = (const float*)d_in[0];
    const float* cw0 = (const float*)d_in[1];
    const float* cw1 = (const float*)d_in[2];
    const float* cw2 = (const float*)d_in[3];
    const float* sw0 = (const float*)d_in[4];
    const float* sw1 = (const float*)d_in[5];
    const float* sw2 = (const float*)d_in[6];
    const float* fw  = (const float*)d_in[7];
    const float* fb  = (const float*)d_in[8];
    const float* gw  = (const float*)d_in[9];
    const float* gb  = (const float*)d_in[10];
    float* out = (float*)d_out;

    float* ws     = (float*)d_ws;
    float* pool16 = ws;                    // 262144
    float* y4     = pool16 + 262144;       // 16384
    float* y8     = y4 + 16384;            // 65536
    float* y16    = y8 + 65536;            // 262144
    float* xp16   = y16 + 262144;          // 262144
    float* xp8    = xp16 + 262144;         // 65536
    float* xp4    = xp8 + 65536;           // 16384
    float* sx     = xp4 + 16384;           // 2048
    float* gramb  = sx + 2048;             // 588 (+ pad to 640)
    double* chanS = (double*)(gramb + 640);   // 2048 doubles (8B-aligned)

    xreadproj_kernel<<<B * C, 256, 0, stream>>>(x, pool16, xp16, xp8, xp4, sx,
                                                gramb);
    site_kernel<<<B * 336, 256, 0, stream>>>(pool16, cw0, cw1, cw2,
                                             sw0, sw1, sw2, fw, y4, y8, y16);
    chanstat_kernel<<<B * C, 256, 0, stream>>>(y4, y8, y16, xp4, xp8, xp16,
                                               sx, fb, gramb, chanS);
    write_kernel<<<B * C * 16, 256, 0, stream>>>(x, y4, y8, y16, fb, gw, gb,
                                                 chanS, out);
}

// Round 19
// 217.615 us; speedup vs baseline: 2.0928x; 1.0935x over previous
//
#include <hip/hip_runtime.h>
#include <hip/hip_bf16.h>
#include <math.h>

#define B 4
#define C 256
#define H 256
#define Wd 256

typedef float vfloat4 __attribute__((ext_vector_type(4)));

// ---------------------------------------------------------------------------
// K1: plane-per-block streaming pass (measured 52.4 us, ~81% of achievable BW;
// unchanged) + Gram/cs precompute tail (validated round 17).
// ---------------------------------------------------------------------------
__global__ __launch_bounds__(256) void xreadproj_kernel(
    const float* __restrict__ x,
    float* __restrict__ pool16, float* __restrict__ xp16o,
    float* __restrict__ xp8o, float* __restrict__ xp4o,
    float* __restrict__ sx, float* __restrict__ gram) {

    __shared__ float P0[16][72];    // p0; guards [64..71]=0
    __shared__ float SS16[16][68];  // [2+l]=S16; guards [0..1],[66..67]=0
    __shared__ float SS8[16][72];   // [4+l]=S8;  guards [0..3],[68..71]=0
    __shared__ float SS4[16][80];   // [8+l]=S4;  guards [0..7],[72..79]=0
    __shared__ float Rs[16 * 29];   // per-slab rowproj, padded stride 29
    __shared__ float rs[4][2];

    int bc = blockIdx.x;
    int t = threadIdx.x;
    int wg = t >> 6, l = t & 63;

    const float4* xp = (const float4*)(x + (size_t)bc * (H * Wd));

    // guard zeros (36 per row; persist across slabs)
    for (int e = t; e < 576; e += 256) {
        int r = e / 36, g = e - r * 36;
        if (g < 8)       P0[r][64 + g] = 0.f;
        else if (g < 10) SS16[r][g - 8] = 0.f;
        else if (g < 12) SS16[r][56 + g] = 0.f;        // 66,67
        else if (g < 16) SS8[r][g - 12] = 0.f;
        else if (g < 20) SS8[r][52 + g] = 0.f;         // 68..71
        else if (g < 28) SS4[r][g - 20] = 0.f;
        else             SS4[r][44 + g] = 0.f;         // 72..79
    }

    // per-lane w-side constants (validated)
    float a16, b16, a8, b8, a4, b4;
    {
        float w0 = 4.f * (float)l + 0.5f;
        float s16v = w0 * 0.0625f - 0.5f;
        if (l <= 1 || l >= 62) { a16 = 0.f; b16 = 0.f; }
        else { a16 = s16v - floorf(s16v); b16 = 0.0625f; }
        float s8v = w0 * 0.03125f - 0.5f;
        if (l <= 3 || l >= 60) { a8 = 0.f; b8 = 0.f; }
        else { a8 = s8v - floorf(s8v); b8 = 0.03125f; }
        float s4v = w0 * 0.015625f - 0.5f;
        if (l <= 7 || l >= 56) { a4 = 0.f; b4 = 0.f; }
        else { a4 = s4v - floorf(s4v); b4 = 0.015625f; }
    }

    // fold-owner indices
    const int i16 = t >> 4, j16 = t & 15;
    const int i8 = t >> 3, j8 = t & 7;              // valid for t<64
    const int i4 = (t - 64) >> 2, j4 = (t - 64) & 3; // valid for 64<=t<80

    float accA = 0.f;   // xp16 entry
    float accB = 0.f;   // xp8 (t<64) or xp4 (64<=t<80)
    float sx1 = 0.f, sx2 = 0.f;

    float4 v[4], vn[4];
#pragma unroll
    for (int it = 0; it < 4; ++it)
        v[it] = xp[(wg * 4 + it) * 64 + l];

#pragma unroll 1
    for (int k = 0; k < 16; ++k) {
        // ---- fold slab k-1 from Rs (validated windows; ascending r) ----
        if (k > 0) {
            int kk = k - 1;
            if (kk >= i16 - 1 && kk <= i16 + 1) {
#pragma unroll
                for (int rl = 0; rl < 16; ++rl) {
                    float src = ((float)(kk * 16 + rl) + 0.5f) * 0.0625f - 0.5f;
                    src = fminf(fmaxf(src, 0.f), 15.f);
                    int lo = (int)src; float fr = src - (float)lo;
                    float w = (i16 == lo) ? (1.f - fr) : ((i16 == lo + 1) ? fr : 0.f);
                    accA += w * Rs[rl * 29 + j16];
                }
            }
            if (t < 64) {
                if (kk >= 2 * i8 - 1 && kk <= 2 * i8 + 2) {
#pragma unroll
                    for (int rl = 0; rl < 16; ++rl) {
                        float src = ((float)(kk * 16 + rl) + 0.5f) * 0.03125f - 0.5f;
                        src = fminf(fmaxf(src, 0.f), 7.f);
                        int lo = (int)src; float fr = src - (float)lo;
                        float w = (i8 == lo) ? (1.f - fr) : ((i8 == lo + 1) ? fr : 0.f);
                        accB += w * Rs[rl * 29 + 16 + j8];
                    }
                }
            } else if (t < 80) {
                if (kk >= 4 * i4 - 2 && kk <= 4 * i4 + 5) {
#pragma unroll
                    for (int rl = 0; rl < 16; ++rl) {
                        float src = ((float)(kk * 16 + rl) + 0.5f) * 0.015625f - 0.5f;
                        src = fminf(fmaxf(src, 0.f), 3.f);
                        int lo = (int)src; float fr = src - (float)lo;
                        float w = (i4 == lo) ? (1.f - fr) : ((i4 == lo + 1) ? fr : 0.f);
                        accB += w * Rs[rl * 29 + 24 + j4];
                    }
                }
            }
        }

        // ---- stage slab k (P0/S only) + sx ----
#pragma unroll
        for (int it = 0; it < 4; ++it) {
            int r = wg * 4 + it;
            float4 vv = v[it];
            float p0 = (vv.x + vv.y) + (vv.z + vv.w);
            float pw = fmaf(3.f, vv.w, fmaf(2.f, vv.z, vv.y));
            sx1 += p0;
            sx2 += vv.x * vv.x + vv.y * vv.y + vv.z * vv.z + vv.w * vv.w;
            P0[r][l]       = p0;
            SS16[r][2 + l] = fmaf(b16, pw, a16 * p0);
            SS8[r][4 + l]  = fmaf(b8,  pw, a8  * p0);
            SS4[r][8 + l]  = fmaf(b4,  pw, a4  * p0);
        }
        __syncthreads();     // barrier A

        // ---- prefetch slab k+1 (after barrier A) ----
        if (k < 15) {
#pragma unroll
            for (int it = 0; it < 4; ++it)
                vn[it] = xp[((k + 1) * 16 + wg * 4 + it) * 64 + l];
        }

        // ---- merge slab k: staging -> Rs + pool16 (validated sums) ----
        for (int tk = t; tk < 464; tk += 256) {
            if (tk < 256) {                       // s16
                int r = tk >> 4, j = tk & 15;
                float sum = 0.f;
#pragma unroll
                for (int q = 0; q < 4; ++q)
                    sum += P0[r][4 * j + 2 + q] - SS16[r][4 * j + 4 + q];
#pragma unroll
                for (int q = 0; q < 4; ++q) sum += SS16[r][4 * j + q];
                if (j == 0) sum += (P0[r][0] - SS16[r][2]) + (P0[r][1] - SS16[r][3]);
                Rs[r * 29 + j] = sum;
            } else if (tk < 384) {                // s8
                int q2 = tk - 256; int r = q2 >> 3, j = q2 & 7;
                float sum = 0.f;
#pragma unroll
                for (int q = 0; q < 8; ++q)
                    sum += P0[r][8 * j + 4 + q] - SS8[r][8 * j + 8 + q];
#pragma unroll
                for (int q = 0; q < 8; ++q) sum += SS8[r][8 * j + q];
                if (j == 0) {
#pragma unroll
                    for (int q = 0; q < 4; ++q) sum += P0[r][q] - SS8[r][4 + q];
                }
                Rs[r * 29 + 16 + j] = sum;
            } else if (tk < 448) {                // s4
                int q2 = tk - 384; int r = q2 >> 2, j = q2 & 3;
                float sum = 0.f;
#pragma unroll
                for (int q = 0; q < 16; ++q)
                    sum += P0[r][16 * j + 8 + q] - SS4[r][16 * j + 16 + q];
#pragma unroll
                for (int q = 0; q < 16; ++q) sum += SS4[r][16 * j + q];
                if (j == 0) {
#pragma unroll
                    for (int q = 0; q < 8; ++q) sum += P0[r][q] - SS4[r][8 + q];
                }
                Rs[r * 29 + 24 + j] = sum;
            } else {                              // pool row
                int j = tk - 448;
                float sum = 0.f;
#pragma unroll
                for (int r2 = 0; r2 < 16; ++r2) {
#pragma unroll
                    for (int q = 0; q < 4; ++q) sum += P0[r2][4 * j + q];
                }
                pool16[(size_t)bc * 256 + k * 16 + j] = sum * (1.f / 256.f);
            }
        }
        __syncthreads();     // barrier B
#pragma unroll
        for (int it = 0; it < 4; ++it) v[it] = vn[it];
    }

    // ---- fold last slab (15) ----
    {
        int kk = 15;
        if (kk >= i16 - 1 && kk <= i16 + 1) {
#pragma unroll
            for (int rl = 0; rl < 16; ++rl) {
                float src = ((float)(kk * 16 + rl) + 0.5f) * 0.0625f - 0.5f;
                src = fminf(fmaxf(src, 0.f), 15.f);
                int lo = (int)src; float fr = src - (float)lo;
                float w = (i16 == lo) ? (1.f - fr) : ((i16 == lo + 1) ? fr : 0.f);
                accA += w * Rs[rl * 29 + j16];
            }
        }
        if (t < 64) {
            if (kk >= 2 * i8 - 1 && kk <= 2 * i8 + 2) {
#pragma unroll
                for (int rl = 0; rl < 16; ++rl) {
                    float src = ((float)(kk * 16 + rl) + 0.5f) * 0.03125f - 0.5f;
                    src = fminf(fmaxf(src, 0.f), 7.f);
                    int lo = (int)src; float fr = src - (float)lo;
                    float w = (i8 == lo) ? (1.f - fr) : ((i8 == lo + 1) ? fr : 0.f);
                    accB += w * Rs[rl * 29 + 16 + j8];
                }
            }
        } else if (t < 80) {
            if (kk >= 4 * i4 - 2 && kk <= 4 * i4 + 5) {
#pragma unroll
                for (int rl = 0; rl < 16; ++rl) {
                    float src = ((float)(kk * 16 + rl) + 0.5f) * 0.015625f - 0.5f;
                    src = fminf(fmaxf(src, 0.f), 3.f);
                    int lo = (int)src; float fr = src - (float)lo;
                    float w = (i4 == lo) ? (1.f - fr) : ((i4 == lo + 1) ? fr : 0.f);
                    accB += w * Rs[rl * 29 + 24 + j4];
                }
            }
        }
    }

    xp16o[(size_t)bc * 256 + t] = accA;
    if (t < 64) xp8o[(size_t)bc * 64 + t] = accB;
    else if (t < 80) xp4o[(size_t)bc * 16 + (t - 64)] = accB;

    // sx: wave reduce (validated pattern)
#pragma unroll
    for (int off = 1; off < 64; off <<= 1) {
        sx1 += __shfl_xor(sx1, off);
        sx2 += __shfl_xor(sx2, off);
    }
    if (l == 0) { rs[wg][0] = sx1; rs[wg][1] = sx2; }
    __syncthreads();
    if (t == 0) {
        sx[bc * 2]     = rs[0][0] + rs[1][0] + rs[2][0] + rs[3][0];
        sx[bc * 2 + 1] = rs[0][1] + rs[1][1] + rs[2][1] + rs[3][1];
    }

    // ---- Gram/cs precompute tail: block bc<588 computes entry bc (wave 0) --
    if (bc < 588 && t < 64) {
        int e = bc;
        float acc = 0.f;
        if (e >= 560) {                 // column sums
            int q = e - 560; int sC, iC;
            if (q < 16) { sC = 16; iC = q; }
            else if (q < 24) { sC = 8; iC = q - 16; }
            else { sC = 4; iC = q - 24; }
            int R = 256 / sC;
            int lo = max(0, R * iC - R / 2), hi = min(256, R * iC + (3 * R) / 2);
            float Rinv = 1.f / (float)R, smax = (float)(sC - 1);
            for (int h = lo + t; h < hi; h += 64) {
                float src = fminf(fmaxf(((float)h + 0.5f) * Rinv - 0.5f, 0.f), smax);
                int lq = (int)src; float fr = src - (float)lq;
                acc += (iC == lq) ? (1.f - fr) : ((iC == lq + 1) ? fr : 0.f);
            }
        } else {                        // Gram entries
            int sA, sB, iA, iB;
            if (e < 256)      { sA = 16; sB = 16; iA = e >> 4; iB = e & 15; }
            else if (e < 384) { int q = e - 256; sA = 16; sB = 8; iA = q >> 3; iB = q & 7; }
            else if (e < 448) { int q = e - 384; sA = 16; sB = 4; iA = q >> 2; iB = q & 3; }
            else if (e < 512) { int q = e - 448; sA = 8;  sB = 8; iA = q >> 3; iB = q & 7; }
            else if (e < 544) { int q = e - 512; sA = 8;  sB = 4; iA = q >> 2; iB = q & 3; }
            else              { int q = e - 544; sA = 4;  sB = 4; iA = q >> 2; iB = q & 3; }
            int RA = 256 / sA, RB = 256 / sB;
            int lo = max(max(0, RA * iA - RA / 2), RB * iB - RB / 2);
            int hi = min(min(256, RA * iA + (3 * RA) / 2), RB * iB + (3 * RB) / 2);
            float RAi = 1.f / (float)RA, RBi = 1.f / (float)RB;
            float smA = (float)(sA - 1), smB = (float)(sB - 1);
            for (int h = lo + t; h < hi; h += 64) {
                float sa = fminf(fmaxf(((float)h + 0.5f) * RAi - 0.5f, 0.f), smA);
                int la = (int)sa; float fa = sa - (float)la;
                float wa = (iA == la) ? (1.f - fa) : ((iA == la + 1) ? fa : 0.f);
                float sb = fminf(fmaxf(((float)h + 0.5f) * RBi - 0.5f, 0.f), smB);
                int lb = (int)sb; float fb_ = sb - (float)lb;
                float wb = (iB == lb) ? (1.f - fb_) : ((iB == lb + 1) ? fb_ : 0.f);
                acc += wa * wb;
            }
        }
#pragma unroll
        for (int off = 1; off < 64; off <<= 1) acc += __shfl_xor(acc, off);
        if (t == 0) gram[e] = acc;
    }
}

// ---------------------------------------------------------------------------
// K2: per (b, scale, site) attention + channel-mix. (unchanged, validated)
// ---------------------------------------------------------------------------
__global__ __launch_bounds__(256) void site_kernel(
    const float* __restrict__ pool16,
    const float* __restrict__ cw0, const float* __restrict__ cw1,
    const float* __restrict__ cw2,
    const float* __restrict__ sw0, const float* __restrict__ sw1,
    const float* __restrict__ sw2,
    const float* __restrict__ fusion_w,
    float* __restrict__ y4, float* __restrict__ y8, float* __restrict__ y16) {

    __shared__ float P[256];
    __shared__ float Wm[961];
    __shared__ float QKV[279];
    __shared__ float QW[93];
    __shared__ float A[9];
    __shared__ float OUTV[93];

    int t = threadIdx.x;
    int blk = blockIdx.x;
    int b = blk / 336;
    int r = blk % 336;

    int s, site, foff;
    const float* cw; const float* sw; float* yout;
    if (r < 256)      { s = 16; site = r;       cw = cw2; sw = sw2; foff = 186; yout = y16; }
    else if (r < 320) { s = 8;  site = r - 256; cw = cw1; sw = sw1; foff = 93;  yout = y8;  }
    else              { s = 4;  site = r - 320; cw = cw0; sw = sw0; foff = 0;   yout = y4;  }
    int i = site / s, j = site % s;

    for (int idx = t; idx < 961; idx += 256) Wm[idx] = sw[idx];

    {
        int f = 16 / s;
        float acc = 0.f;
        int base = (b * 256 + t) * 256;
        for (int ii = 0; ii < f; ++ii)
            for (int jj = 0; jj < f; ++jj)
                acc += pool16[base + (i * f + ii) * 16 + (j * f + jj)];
        P[t] = acc / (float)(f * f);
    }
    __syncthreads();

    for (int o = t; o < 279; o += 256) {
        const float4* wrow = (const float4*)(cw + o * 256);
        float acc = 0.f;
#pragma unroll 8
        for (int c4 = 0; c4 < 64; ++c4) {
            float4 wv = wrow[c4];
            acc += wv.x * P[c4 * 4] + wv.y * P[c4 * 4 + 1] +
                   wv.z * P[c4 * 4 + 2] + wv.w * P[c4 * 4 + 3];
        }
        QKV[o] = acc;
    }
    __syncthreads();

    if (t < 93) {
        int g = t / 31, m = t % 31;
        float acc = 0.f;
        for (int n = 0; n < 31; ++n) acc += QKV[g * 31 + n] * Wm[n * 31 + m];
        QW[t] = acc;
    }
    __syncthreads();
    if (t < 9) {
        int g = t / 3, h = t % 3;
        float acc = 0.f;
        for (int m = 0; m < 31; ++m) acc += QW[g * 31 + m] * QKV[93 + h * 31 + m];
        A[t] = acc * 0.57735026918962576f;
    }
    __syncthreads();
    if (t < 3) {
        float a0 = A[t * 3], a1 = A[t * 3 + 1], a2 = A[t * 3 + 2];
        float mx = fmaxf(a0, fmaxf(a1, a2));
        float e0 = expf(a0 - mx), e1 = expf(a1 - mx), e2 = expf(a2 - mx);
        float inv = 1.0f / (e0 + e1 + e2);
        A[t * 3] = e0 * inv; A[t * 3 + 1] = e1 * inv; A[t * 3 + 2] = e2 * inv;
    }
    __syncthreads();
    if (t < 93) {
        int g = t / 31, n = t % 31;
        OUTV[t] = A[g * 3] * QKV[186 + n] + A[g * 3 + 1] * QKV[186 + 31 + n] +
                  A[g * 3 + 2] * QKV[186 + 62 + n];
    }
    __syncthreads();
    {
        const float* fr = fusion_w + t * 279 + foff;
        float acc = 0.f;
#pragma unroll 31
        for (int c = 0; c < 93; ++c) acc += fr[c] * OUTV[c];
        yout[(size_t)(b * 256 + t) * (s * s) + site] = acc;
    }
}

// ---------------------------------------------------------------------------
// K3: per-CHANNEL stats (1024 blocks; Gram loaded from gram[]; validated r17).
// ---------------------------------------------------------------------------
__global__ __launch_bounds__(256) void chanstat_kernel(
    const float* __restrict__ y4, const float* __restrict__ y8,
    const float* __restrict__ y16,
    const float* __restrict__ xp4, const float* __restrict__ xp8,
    const float* __restrict__ xp16,
    const float* __restrict__ sx, const float* __restrict__ fusion_b,
    const float* __restrict__ gram,
    double* __restrict__ chanS) {

    __shared__ float Gs[588];
    __shared__ float ybuf[336], xbuf[336];
    __shared__ float Tm[256];
    __shared__ float red[8];

    int t = threadIdx.x;
    int bc = blockIdx.x;          // b*256 + c

    for (int e = t; e < 588; e += 256) Gs[e] = gram[e];

    const float* G1616 = Gs;
    const float* G168  = Gs + 256;
    const float* G164  = Gs + 384;
    const float* G88   = Gs + 448;
    const float* G84   = Gs + 512;
    const float* G44   = Gs + 544;
    const float* cs    = Gs + 560;

    size_t bcs = (size_t)bc;
    ybuf[t] = y16[bcs * 256 + t];
    xbuf[t] = xp16[bcs * 256 + t];
    if (t < 64) { ybuf[256 + t] = y8[bcs * 64 + t]; xbuf[256 + t] = xp8[bcs * 64 + t]; }
    else if (t < 80) { ybuf[256 + t] = y4[bcs * 16 + (t - 64)]; xbuf[256 + t] = xp4[bcs * 16 + (t - 64)]; }
    __syncthreads();

    float pu = 0.f, pv = 0.f;
    for (int e = t; e < 336; e += 256) {
        float yv = ybuf[e];
        pv += 2.f * yv * xbuf[e];
        int ci, cj;
        if (e < 256)      { ci = e >> 4;               cj = e & 15; }
        else if (e < 320) { ci = 16 + ((e - 256) >> 3); cj = 16 + ((e - 256) & 7); }
        else              { ci = 24 + ((e - 320) >> 2); cj = 24 + ((e - 320) & 3); }
        pu += yv * cs[ci] * cs[cj];
    }

    for (int p = 0; p < 6; ++p) {
        const float* Gp; int sA, sB, yAoff, yBoff; float factor;
        switch (p) {
            case 0: Gp = G1616; sA = 16; sB = 16; yAoff = 0;   yBoff = 0;   factor = 1.f; break;
            case 1: Gp = G168;  sA = 16; sB = 8;  yAoff = 0;   yBoff = 256; factor = 2.f; break;
            case 2: Gp = G164;  sA = 16; sB = 4;  yAoff = 0;   yBoff = 320; factor = 2.f; break;
            case 3: Gp = G88;   sA = 8;  sB = 8;  yAoff = 256; yBoff = 256; factor = 1.f; break;
            case 4: Gp = G84;   sA = 8;  sB = 4;  yAoff = 256; yBoff = 320; factor = 2.f; break;
            default:Gp = G44;   sA = 4;  sB = 4;  yAoff = 320; yBoff = 320; factor = 1.f; break;
        }
        __syncthreads();
        int nT = sB * sA;
        if (t < nT) {
            int iB = t / sA, jA = t - iB * sA;
            float a = 0.f;
            for (int jB = 0; jB < sB; ++jB)
                a += Gp[jA * sB + jB] * ybuf[yBoff + iB * sB + jB];
            Tm[t] = a;
        }
        __syncthreads();
        int nB = sA * sA;
        if (t < nB) {
            int iA = t / sA, jA = t - iA * sA;
            float a = 0.f;
            for (int iB = 0; iB < sB; ++iB)
                a += Gp[iA * sB + iB] * Tm[iB * sA + jA];
            pv += factor * ybuf[yAoff + t] * a;
        }
    }

#pragma unroll
    for (int off = 1; off < 64; off <<= 1) {
        pu += __shfl_xor(pu, off);
        pv += __shfl_xor(pv, off);
    }
    __syncthreads();
    if ((t & 63) == 0) { red[(t >> 6) * 2] = pu; red[(t >> 6) * 2 + 1] = pv; }
    __syncthreads();
    if (t == 0) {
        float puT = red[0] + red[2] + red[4] + red[6];
        float pvT = red[1] + red[3] + red[5] + red[7];
        float fb = fusion_b[bc & 255];
        float s1 = sx[bc * 2], s2 = sx[bc * 2 + 1];
        double S1 = (double)s1 + 65536.0 * (double)fb + (double)puT;
        double S2 = (double)s2 + 2.0 * (double)fb * (double)s1 +
                    65536.0 * (double)fb * (double)fb +
                    2.0 * (double)fb * (double)puT + (double)pvT;
        chanS[bc * 2] = S1;
        chanS[bc * 2 + 1] = S2;
    }
}

// ---------------------------------------------------------------------------
// K4: final pass (round-17 version; ONE change: NON-TEMPORAL out stores via
// clang ext_vector_type so the 268 MB of out never allocates into L2/L3 ->
// x's L3-resident tail survives for the reversed-order read).
// ---------------------------------------------------------------------------
__global__ __launch_bounds__(256) void write_kernel(
    const float* __restrict__ x,
    const float* __restrict__ ws_y4, const float* __restrict__ ws_y8,
    const float* __restrict__ ws_y16,
    const float* __restrict__ fusion_b,
    const float* __restrict__ gn_w, const float* __restrict__ gn_b,
    const double* __restrict__ chanS,
    float* __restrict__ out) {

    __shared__ float ly16[256], ly8[64], ly4[16];
    __shared__ float2 rbd16[16][16];
    __shared__ float2 rbd8[16][8];
    __shared__ float2 rbd4[16][4];
    __shared__ float sstat[2];

    int blk = (B * C * 16 - 1) - blockIdx.x;   // reversed: L3 ping-pong
    int hblk = blk & 15;
    int c = (blk >> 4) & 255;
    int b = blk >> 12;
    int t = threadIdx.x;

    if (t == 0) {   // group stats from chanS (gnfold arithmetic, same order)
        int gidx = c >> 3;
        const double* cS = chanS + ((size_t)(b * 256 + gidx * 8)) * 2;
        double gS1 = 0.0, gS2 = 0.0;
#pragma unroll
        for (int c8 = 0; c8 < 8; ++c8) {
            gS1 += cS[c8 * 2];
            gS2 += cS[c8 * 2 + 1];
        }
        double meand = gS1 / 524288.0;
        double vard  = gS2 / 524288.0 - meand * meand;
        sstat[0] = (float)meand;
        sstat[1] = (float)(1.0 / sqrt(vard + 1e-5));
    }

    ly16[t] = ws_y16[(size_t)(b * 256 + c) * 256 + t];
    if (t < 64) ly8[t] = ws_y8[(size_t)(b * 256 + c) * 64 + t];
    if (t < 16) ly4[t] = ws_y4[(size_t)(b * 256 + c) * 16 + t];
    __syncthreads();

    for (int idx = t; idx < 448; idx += 256) {
        int r = idx / 28;
        int q = idx - r * 28;
        int h = hblk * 16 + r;
        if (q < 16) {
            float src = (h + 0.5f) * 0.0625f - 0.5f;
            src = fminf(fmaxf(src, 0.f), 15.f);
            int lo = (int)src; float wf = src - lo; int hi = min(lo + 1, 15);
            float rb = (1.f - wf) * ly16[lo * 16 + q] + wf * ly16[hi * 16 + q];
            rbd16[r][q].x = rb;
            if (q > 0) rbd16[r][q - 1].y = rb;
            if (q == 15) rbd16[r][15].y = rb;
        } else if (q < 24) {
            int jj = q - 16;
            float src = (h + 0.5f) * 0.03125f - 0.5f;
            src = fminf(fmaxf(src, 0.f), 7.f);
            int lo = (int)src; float wf = src - lo; int hi = min(lo + 1, 7);
            float rb = (1.f - wf) * ly8[lo * 8 + jj] + wf * ly8[hi * 8 + jj];
            rbd8[r][jj].x = rb;
            if (jj > 0) rbd8[r][jj - 1].y = rb;
            if (jj == 7) rbd8[r][7].y = rb;
        } else {
            int jj = q - 24;
            float src = (h + 0.5f) * 0.015625f - 0.5f;
            src = fminf(fmaxf(src, 0.f), 3.f);
            int lo = (int)src; float wf = src - lo; int hi = min(lo + 1, 3);
            float rb = (1.f - wf) * ly4[lo * 4 + jj] + wf * ly4[hi * 4 + jj];
            rbd4[r][jj].x = rb;
            if (jj > 0) rbd4[r][jj - 1].y = rb;
            if (jj == 3) rbd4[r][3].y = rb;
        }
    }
    __syncthreads();

    int w4 = t & 63;
    int wg = t >> 6;
    int w0 = w4 * 4;

    int jlo16[4], jlo8[4], jlo4[4];
    float ww16[4], ww8[4], ww4[4];
#pragma unroll
    for (int p = 0; p < 4; ++p) {
        int w = w0 + p;
        float s16 = fminf(fmaxf((w + 0.5f) * 0.0625f - 0.5f, 0.f), 15.f);
        jlo16[p] = (int)s16; ww16[p] = s16 - jlo16[p];
        float s8 = fminf(fmaxf((w + 0.5f) * 0.03125f - 0.5f, 0.f), 7.f);
        jlo8[p] = (int)s8; ww8[p] = s8 - jlo8[p];
        float s4 = fminf(fmaxf((w + 0.5f) * 0.015625f - 0.5f, 0.f), 3.f);
        jlo4[p] = (int)s4; ww4[p] = s4 - jlo4[p];
    }

    float fb_c = fusion_b[c];
    float mean = sstat[0];
    float rstd = sstat[1];
    float gwc = gn_w[c], gbc = gn_b[c];

    const float4* xp = (const float4*)(x + (size_t)(b * 256 + c) * (H * Wd));
    vfloat4* op = (vfloat4*)(out + (size_t)(b * 256 + c) * (H * Wd));

#pragma unroll
    for (int it = 0; it < 4; ++it) {
        int r = it * 4 + wg;
        int idx4 = (hblk * 16 + r) * 64 + w4;
        float4 xv = xp[idx4];
        float res[4];
        float px[4] = {xv.x, xv.y, xv.z, xv.w};
#pragma unroll
        for (int p = 0; p < 4; ++p) {
            float f = fb_c;
            float2 v16 = rbd16[r][jlo16[p]];
            f += (1.f - ww16[p]) * v16.x + ww16[p] * v16.y;
            float2 v8 = rbd8[r][jlo8[p]];
            f += (1.f - ww8[p]) * v8.x + ww8[p] * v8.y;
            float2 v4 = rbd4[r][jlo4[p]];
            f += (1.f - ww4[p]) * v4.x + ww4[p] * v4.y;
            float tv = px[p] + f;
            res[p] = (tv - mean) * rstd * gwc + gbc;
        }
        vfloat4 r4;
        r4.x = res[0]; r4.y = res[1]; r4.z = res[2]; r4.w = res[3];
        __builtin_nontemporal_store(r4, &op[idx4]);
    }
}

// ---------------------------------------------------------------------------
extern "C" void kernel_launch(void* const* d_in, const int* in_sizes, int n_in,
                              void* d_out, int out_size, void* d_ws, size_t ws_size,
                              hipStream_t stream) {
    const float* x   = (const float*)d_in[0];
    const float* cw0 = (const float*)d_in[1];
    const float* cw1 = (const float*)d_in[2];
    const float* cw2 = (const float*)d_in[3];
    const float* sw0 = (const float*)d_in[4];
    const float* sw1 = (const float*)d_in[5];
    const float* sw2 = (const float*)d_in[6];
    const float* fw  = (const float*)d_in[7];
    const float* fb  = (const float*)d_in[8];
    const float* gw  = (const float*)d_in[9];
    const float* gb  = (const float*)d_in[10];
    float* out = (float*)d_out;

    float* ws     = (float*)d_ws;
    float* pool16 = ws;                    // 262144
    float* y4     = pool16 + 262144;       // 16384
    float* y8     = y4 + 16384;            // 65536
    float* y16    = y8 + 65536;            // 262144
    float* xp16   = y16 + 262144;          // 262144
    float* xp8    = xp16 + 262144;         // 65536
    float* xp4    = xp8 + 65536;           // 16384
    float* sx     = xp4 + 16384;           // 2048
    float* gramb  = sx + 2048;             // 588 (+ pad to 640)
    double* chanS = (double*)(gramb + 640);   // 2048 doubles (8B-aligned)

    xreadproj_kernel<<<B * C, 256, 0, stream>>>(x, pool16, xp16, xp8, xp4, sx,
                                                gramb);
    site_kernel<<<B * 336, 256, 0, stream>>>(pool16, cw0, cw1, cw2,
                                             sw0, sw1, sw2, fw, y4, y8, y16);
    chanstat_kernel<<<B * C, 256, 0, stream>>>(y4, y8, y16, xp4, xp8, xp16,
                                               sx, fb, gramb, chanS);
    write_kernel<<<B * C * 16, 256, 0, stream>>>(x, y4, y8, y16, fb, gw, gb,
                                                 chanS, out);
}